// Round 20
// baseline (67.653 us; speedup 1.0000x reference)
//
#include <hip/hip_runtime.h>
#include <hip/hip_bf16.h>
#include <hip/hip_cooperative_groups.h>

namespace cg = cooperative_groups;

#define N_NODES 100000
#define N_EDGES 800000
#define D 64
#define SLICES 64                 // edge slices
#define QUARTERS 4                // node-range quarters
#define NQUART 25000              // nodes per quarter
#define HWORDS_Q 6272             // u8-packed words/quarter (25 KB)
#define QUADS (N_EDGES / 4)       // 200000 quad-edge groups
#define QPS (QUADS / SLICES)      // 3125 quads per slice
#define XPAD 72                   // bf16 row stride: conflict-free frag reads
#define TILE 256                  // proj nodes per tile
#define N_TILES ((N_NODES + TILE - 1) / TILE)  // 391
#define GRID 256                  // cooperative grid: 1 block/CU

typedef __attribute__((ext_vector_type(8))) short bf16x8;
typedef __attribute__((ext_vector_type(4))) float f32x4;

// ---------------------------------------------------------------------------
// softmax(axis=1) over [E,1] == 1.0 identically, so
//   z[n] = count[n] * (node_features[n] @ W_n^T + b_n)
// where count[n] = #edges with node0_idx == n. Attention branch is dead code.
//
// Ledger (R18/R19): P_kernel ~9.3 (AT its 9.1us BW floor), H_kernel ~3.8
// (latency floor; two throughput fixes neutral), remainder ~10us = dispatch
// boundaries + fixed replay overhead. R20: collapse 2 dispatches -> 1 via
// hipLaunchCooperativeKernel + grid.sync() (guide-sanctioned; R4's failure
// was a hand-rolled spin barrier, not the cooperative API).
//   Phase 1: hist, exact R17 shape (256 blk x 1024 thr, 25KB u8 LDS bins).
//   Phase 2: MFMA proj, 256-node tiles x 391, grid-stride, same wave work.
// LDS phases aliased in one 49KB buffer (1 block/CU needed; 2 fit).
// ---------------------------------------------------------------------------

// f32 -> bf16 (round-to-nearest-even), packed pair
__device__ inline unsigned bf16rn(float f) {
    const unsigned u = __float_as_uint(f);
    return (u + 0x7FFFu + ((u >> 16) & 1u)) >> 16;
}
__device__ inline unsigned pk2(float lo, float hi) {
    return bf16rn(lo) | (bf16rn(hi) << 16);
}

#define SMEM_BYTES 50176  // max(hist 25088, proj 36864+9216+4096)

__global__ __launch_bounds__(1024, 2) void fused_kernel(
        const int*   __restrict__ idx32,  // [2, N_EDGES] int64 or int32
        const float* __restrict__ nf,     // [N_NODES, 64]
        const float* __restrict__ Wn,     // [64, 64] row-major
        const float* __restrict__ bn,     // [64]
        unsigned*    __restrict__ part,   // [SLICES*QUARTERS][HWORDS_Q]
        float*       __restrict__ out) {  // [N_NODES, 64]
    __shared__ __align__(16) unsigned char smem[SMEM_BYTES];
    const int t = threadIdx.x;
    const int lane = t & 63;
    cg::grid_group grid = cg::this_grid();

    // ================= Phase 1: histogram (R17 shape) =================
    {
        unsigned* __restrict__ h = (unsigned*)smem;  // 25 KB u8-packed bins
        uint4* __restrict__ h4 = (uint4*)smem;
        for (int i = t; i < HWORDS_Q / 4; i += 1024)
            h4[i] = uint4{0u, 0u, 0u, 0u};

        // int64/int32 detection: LE int64 values in [0,N_NODES) have all
        // odd int32 words zero. 256 sampled odd words; wave ballot-OR.
        int s = 0;
#pragma unroll
        for (int k = 0; k < 4; ++k) s |= idx32[2 * (lane + 64 * k) + 1];
        const bool is64 = (__ballot(s != 0) == 0ULL);  // wave-uniform

        __syncthreads();

        const int slice = blockIdx.x >> 2;
        const int q     = blockIdx.x & 3;
        const int base  = q * NQUART;

        for (int tq = slice * QPS + t; tq < (slice + 1) * QPS; tq += 1024) {
            int v[4];
            if (is64) {
                const int4 a = ((const int4*)idx32)[2 * tq + 0];
                const int4 b = ((const int4*)idx32)[2 * tq + 1];
                v[0] = a.x; v[1] = a.z; v[2] = b.x; v[3] = b.z;
            } else {
                const int4 a = ((const int4*)idx32)[tq];
                v[0] = a.x; v[1] = a.y; v[2] = a.z; v[3] = a.w;
            }
#pragma unroll
            for (int j = 0; j < 4; ++j) {
                const unsigned u = (unsigned)(v[j] - base);
                if (u < (unsigned)NQUART)
                    atomicAdd(&h[u >> 2], 1u << (8 * (u & 3)));  // LDS atomic
            }
        }

        __syncthreads();

        uint4* __restrict__ dst =
            (uint4*)(part + (size_t)blockIdx.x * HWORDS_Q);
        for (int i = t; i < HWORDS_Q / 4; i += 1024) dst[i] = h4[i];
    }

    grid.sync();  // all partials visible device-wide

    // ================= Phase 2: MFMA projection =================
    unsigned short* __restrict__ xs = (unsigned short*)smem;            // 36864
    unsigned short* __restrict__ wl = (unsigned short*)(smem + 36864);  // 9216
    unsigned* __restrict__ cnt_p = (unsigned*)(smem + 36864 + 9216);    // [16][64]

    const int wv = __builtin_amdgcn_readfirstlane(t >> 6);  // 0..15
    const int l15 = lane & 15;
    const int lhi = lane >> 4;  // 0..3

    // stage W once: threads 0..255, 4/row, f32 -> bf16, 2 b128 writes
    if (t < 256) {
        const int r = t >> 2;
        const int c0 = (t & 3) * 16;
        const float* __restrict__ src = Wn + r * D + c0;
        const float4 v0 = *reinterpret_cast<const float4*>(src + 0);
        const float4 v1 = *reinterpret_cast<const float4*>(src + 4);
        const float4 v2 = *reinterpret_cast<const float4*>(src + 8);
        const float4 v3 = *reinterpret_cast<const float4*>(src + 12);
        uint4 lo, hi;
        lo.x = pk2(v0.x, v0.y); lo.y = pk2(v0.z, v0.w);
        lo.z = pk2(v1.x, v1.y); lo.w = pk2(v1.z, v1.w);
        hi.x = pk2(v2.x, v2.y); hi.y = pk2(v2.z, v2.w);
        hi.z = pk2(v3.x, v3.y); hi.w = pk2(v3.z, v3.w);
        *reinterpret_cast<uint4*>(&wl[r * XPAD + c0 + 0]) = lo;
        *reinterpret_cast<uint4*>(&wl[r * XPAD + c0 + 8]) = hi;
    }

    // bias per output col (uniform per lane across tiles) -> hoist
    float bias[4];
#pragma unroll
    for (int nt = 0; nt < 4; ++nt) bias[nt] = bn[nt * 16 + l15];

    for (int tile = blockIdx.x; tile < N_TILES; tile += GRID) {
        const int tbase = tile * TILE;

        __syncthreads();  // previous-iter reads done; wl staged (iter 0)

        // stage x tile: 256 rows x 64 f32 -> bf16; 4 threads/row
        {
            const int r = t >> 2;                       // 0..255
            const int c0 = (t & 3) * 16;
            const int node = min(tbase + r, N_NODES - 1);
            const float* __restrict__ src = nf + (size_t)node * D + c0;
            const float4 v0 = *reinterpret_cast<const float4*>(src + 0);
            const float4 v1 = *reinterpret_cast<const float4*>(src + 4);
            const float4 v2 = *reinterpret_cast<const float4*>(src + 8);
            const float4 v3 = *reinterpret_cast<const float4*>(src + 12);
            uint4 lo, hi;
            lo.x = pk2(v0.x, v0.y); lo.y = pk2(v0.z, v0.w);
            lo.z = pk2(v1.x, v1.y); lo.w = pk2(v1.z, v1.w);
            hi.x = pk2(v2.x, v2.y); hi.y = pk2(v2.z, v2.w);
            hi.z = pk2(v3.x, v3.y); hi.w = pk2(v3.z, v3.w);
            *reinterpret_cast<uint4*>(&xs[r * XPAD + c0 + 0]) = lo;
            *reinterpret_cast<uint4*>(&xs[r * XPAD + c0 + 8]) = hi;
        }

        // merge-fold: wave wv covers nodes [16wv,16wv+16); lane = (sg,i):
        // sg = lhi sums slices [16sg,16sg+16) for node i = l15.
        {
            const int node = min(tbase + wv * 16 + l15, N_NODES - 1);
            const int q = node / NQUART;
            const int lw = (node - q * NQUART) >> 2;
            const int sh = 8 * (node & 3);
            unsigned s = 0;
#pragma unroll
            for (int k = 0; k < 16; ++k) {
                const int b = 16 * lhi + k;  // slice
                s += (part[(size_t)(4 * b + q) * HWORDS_Q + lw] >> sh) & 255u;
            }
            cnt_p[wv * 64 + lhi * 16 + l15] = s;
        }

        __syncthreads();

        // MFMA: wave wv -> m-rows [16wv, 16wv+16) of this tile
        const unsigned short* __restrict__ arow =
            &xs[(wv * 16 + l15) * XPAD + lhi * 8];
        const bf16x8 a0 = *reinterpret_cast<const bf16x8*>(arow + 0);
        const bf16x8 a1 = *reinterpret_cast<const bf16x8*>(arow + 32);

        f32x4 acc[4];
#pragma unroll
        for (int nt = 0; nt < 4; ++nt)
            acc[nt] = f32x4{bias[nt], bias[nt], bias[nt], bias[nt]};

#pragma unroll
        for (int nt = 0; nt < 4; ++nt) {
            const unsigned short* __restrict__ brow =
                &wl[(nt * 16 + l15) * XPAD + lhi * 8];
            const bf16x8 b0 = *reinterpret_cast<const bf16x8*>(brow + 0);
            const bf16x8 b1 = *reinterpret_cast<const bf16x8*>(brow + 32);
            acc[nt] = __builtin_amdgcn_mfma_f32_16x16x32_bf16(a0, b0, acc[nt], 0, 0, 0);
            acc[nt] = __builtin_amdgcn_mfma_f32_16x16x32_bf16(a1, b1, acc[nt], 0, 0, 0);
        }

        // counts for this lane's 4 output rows: i = lhi*4 + r
        float cf[4];
#pragma unroll
        for (int r = 0; r < 4; ++r) {
            const int i = lhi * 4 + r;
            cf[r] = (float)(cnt_p[wv * 64 + 0 + i] + cnt_p[wv * 64 + 16 + i] +
                            cnt_p[wv * 64 + 32 + i] + cnt_p[wv * 64 + 48 + i]);
        }

        // store: node = tbase + 16wv + lhi*4 + r, col = nt*16 + l15
#pragma unroll
        for (int nt = 0; nt < 4; ++nt) {
#pragma unroll
            for (int r = 0; r < 4; ++r) {
                const int node = tbase + wv * 16 + lhi * 4 + r;
                if (node < N_NODES)
                    out[(size_t)node * D + nt * 16 + l15] = cf[r] * acc[nt][r];
            }
        }
    }
}

extern "C" void kernel_launch(void* const* d_in, const int* in_sizes, int n_in,
                              void* d_out, int out_size, void* d_ws, size_t ws_size,
                              hipStream_t stream) {
    const int*   eidx = (const int*)d_in[1];    // [2, 800000] int64 or int32
    const float* nf   = (const float*)d_in[0];  // [100000, 64]
    const float* Wn   = (const float*)d_in[3];  // [64, 64]
    const float* bn   = (const float*)d_in[4];  // [64]
    float* out = (float*)d_out;                 // [100000, 64] f32

    unsigned* part = (unsigned*)d_ws;  // 256 x 25 KB = 6.42 MB slice-partials

    void* args[] = {(void*)&eidx, (void*)&nf, (void*)&Wn,
                    (void*)&bn, (void*)&part, (void*)&out};
    hipLaunchCooperativeKernel((void*)fused_kernel, dim3(GRID), dim3(1024),
                               args, 0, stream);
}

// Round 21
// 24.474 us; speedup vs baseline: 2.7642x; 2.7642x over previous
//
#include <hip/hip_runtime.h>
#include <hip/hip_bf16.h>

#define N_NODES 100000
#define N_EDGES 800000
#define D 64
#define SLICES 64                 // edge slices
#define QUARTERS 4                // node-range quarters
#define HIST_BLOCKS (SLICES * QUARTERS)  // 256 = full GPU
#define NQUART 25000              // nodes per quarter
#define HWORDS_Q 6272             // u8-packed words/quarter, padded to /4 (25 KB)
#define QUADS (N_EDGES / 4)       // 200000 quad-edge groups
#define QPS (QUADS / SLICES)      // 3125 quads per slice
#define XPAD 72                   // bf16 row stride: conflict-free frag reads

typedef __attribute__((ext_vector_type(8))) short bf16x8;
typedef __attribute__((ext_vector_type(4))) float f32x4;

// ---------------------------------------------------------------------------
// softmax(axis=1) over [E,1] == 1.0 identically, so
//   z[n] = count[n] * (node_features[n] @ W_n^T + b_n)
// where count[n] = #edges with node0_idx == n. Attention branch is dead code.
//
// FINAL (revert to R17 best-known, 24.34 us). Ledger from amplification
// measurements (R9/R13/R18) and deltas (R3/R19):
//   P (MFMA proj)  ~9.3-11 us  -> AT its 9.1us mixed-R/W BW floor
//   H (LDS hist)   ~3.8-5.8 us -> latency floor (throughput fixes neutral)
//   G (replay+dispatch overhead) ~7-10 us -> structural; fusion attempts
//       via spin-barrier (R4: +85us) and cooperative grid.sync (R20: +43us)
//       BOTH regressed -- kernel-boundary cost < any in-kernel global sync.
// History: 121.8 (R1) -> 24.3 us via: dead-code elimination of the entire
// attention branch (softmax over [E,1] == 1), LDS-privatized histogram
// (global atomics = 43us of memory-side RMW), merge folded into proj, and
// bf16 MFMA projection (f32 vector-FMA operand delivery was the wall:
// LDS-broadcast 24.6us / s_load 19.8us / uniform-VMEM ~29us all stall-bound;
// MFMA fragments move 1KB/ds_read_b128 and transpose in the crossbar).
// ---------------------------------------------------------------------------

__global__ __launch_bounds__(1024) void hist_kernel(
        const int* __restrict__ idx32,   // [2, N_EDGES] int64 or int32
        unsigned*  __restrict__ part) {  // [HIST_BLOCKS][HWORDS_Q]
    __shared__ __align__(16) unsigned h[HWORDS_Q];  // 25 KB, u8-packed
    uint4* __restrict__ h4 = (uint4*)h;
    for (int i = threadIdx.x; i < HWORDS_Q / 4; i += 1024)
        h4[i] = uint4{0u, 0u, 0u, 0u};

    // int64/int32 detection: for LE int64 values in [0,N_NODES) all odd
    // int32 words are 0. Each wave samples 256 odd words; ballot-OR.
    const int lane = threadIdx.x & 63;
    int s = 0;
#pragma unroll
    for (int k = 0; k < 4; ++k) s |= idx32[2 * (lane + 64 * k) + 1];
    const bool is64 = (__ballot(s != 0) == 0ULL);  // wave-uniform

    __syncthreads();

    const int slice = blockIdx.x >> 2;
    const int q     = blockIdx.x & 3;
    const int base  = q * NQUART;

    // 4 edges per iteration, vectorized loads. Count only our quarter-range.
    for (int t = slice * QPS + threadIdx.x; t < (slice + 1) * QPS; t += 1024) {
        int v[4];
        if (is64) {
            const int4 a = ((const int4*)idx32)[2 * t + 0];  // edges 4t,4t+1
            const int4 b = ((const int4*)idx32)[2 * t + 1];  // edges 4t+2,+3
            v[0] = a.x; v[1] = a.z; v[2] = b.x; v[3] = b.z;
        } else {
            const int4 a = ((const int4*)idx32)[t];
            v[0] = a.x; v[1] = a.y; v[2] = a.z; v[3] = a.w;
        }
#pragma unroll
        for (int j = 0; j < 4; ++j) {
            const unsigned u = (unsigned)(v[j] - base);
            if (u < (unsigned)NQUART)
                atomicAdd(&h[u >> 2], 1u << (8 * (u & 3)));  // LDS atomic
        }
    }

    __syncthreads();

    // stream partial to global, 16B stores (HWORDS_Q/4 = 1568 uint4)
    uint4* __restrict__ dst = (uint4*)(part + (size_t)blockIdx.x * HWORDS_Q);
    for (int i = threadIdx.x; i < HWORDS_Q / 4; i += 1024) dst[i] = h4[i];
}

// f32 -> bf16 (round-to-nearest-even), packed pair
__device__ inline unsigned bf16rn(float f) {
    const unsigned u = __float_as_uint(f);
    return (u + 0x7FFFu + ((u >> 16) & 1u)) >> 16;
}
__device__ inline unsigned pk2(float lo, float hi) {
    return bf16rn(lo) | (bf16rn(hi) << 16);
}

// Block = 256 threads = 4 waves; block handles 64 nodes (M=64), 64 outputs.
// Wave wv = m-tile (16 nodes); per wave: 4 n-tiles x 2 K-steps of
// mfma_f32_16x16x32_bf16. x,W live in LDS as bf16 [64][XPAD].
__global__ __launch_bounds__(256, 4) void proj_kernel(
        const float* __restrict__ nf,       // [N_NODES, 64]
        const float* __restrict__ Wn,       // [64, 64] row-major
        const float* __restrict__ bn,       // [64]
        const unsigned* __restrict__ part,  // [HIST_BLOCKS][HWORDS_Q]
        float* __restrict__ out) {          // [N_NODES, 64]
    __shared__ __align__(16) unsigned short xs[64 * XPAD];  // 9216 B
    __shared__ __align__(16) unsigned short wl[64 * XPAD];  // 9216 B
    __shared__ unsigned cnt_p[4][64];                       // merge-fold

    const int t = threadIdx.x;
    const int base = blockIdx.x * 64;
    const int lane = t & 63;
    const int wv = __builtin_amdgcn_readfirstlane(t >> 6);  // 0..3

    // ---- stage W: 4 threads/row, 16 f32 -> 16 bf16 each, 2 b128 writes ----
    {
        const int r = t >> 2;
        const int c0 = (t & 3) * 16;
        const float* __restrict__ src = Wn + r * D + c0;
        const float4 v0 = *reinterpret_cast<const float4*>(src + 0);
        const float4 v1 = *reinterpret_cast<const float4*>(src + 4);
        const float4 v2 = *reinterpret_cast<const float4*>(src + 8);
        const float4 v3 = *reinterpret_cast<const float4*>(src + 12);
        uint4 lo, hi;
        lo.x = pk2(v0.x, v0.y); lo.y = pk2(v0.z, v0.w);
        lo.z = pk2(v1.x, v1.y); lo.w = pk2(v1.z, v1.w);
        hi.x = pk2(v2.x, v2.y); hi.y = pk2(v2.z, v2.w);
        hi.z = pk2(v3.x, v3.y); hi.w = pk2(v3.z, v3.w);
        *reinterpret_cast<uint4*>(&wl[r * XPAD + c0 + 0]) = lo;
        *reinterpret_cast<uint4*>(&wl[r * XPAD + c0 + 8]) = hi;
    }

    // ---- stage x tile: same pattern, clamped tail rows ----
    {
        const int r = t >> 2;
        const int c0 = (t & 3) * 16;
        const int node = min(base + r, N_NODES - 1);
        const float* __restrict__ src = nf + (size_t)node * D + c0;
        const float4 v0 = *reinterpret_cast<const float4*>(src + 0);
        const float4 v1 = *reinterpret_cast<const float4*>(src + 4);
        const float4 v2 = *reinterpret_cast<const float4*>(src + 8);
        const float4 v3 = *reinterpret_cast<const float4*>(src + 12);
        uint4 lo, hi;
        lo.x = pk2(v0.x, v0.y); lo.y = pk2(v0.z, v0.w);
        lo.z = pk2(v1.x, v1.y); lo.w = pk2(v1.z, v1.w);
        hi.x = pk2(v2.x, v2.y); hi.y = pk2(v2.z, v2.w);
        hi.z = pk2(v3.x, v3.y); hi.w = pk2(v3.z, v3.w);
        *reinterpret_cast<uint4*>(&xs[r * XPAD + c0 + 0]) = lo;
        *reinterpret_cast<uint4*>(&xs[r * XPAD + c0 + 8]) = hi;
    }

    // ---- merge-fold: wave wv sums slice-partials [16wv,16wv+16) for its
    //      lane's node (clamped on tail; unused there). ----
    {
        const int node = min(base + lane, N_NODES - 1);
        const int q = node / NQUART;
        const int lw = (node - q * NQUART) >> 2;
        const int sh = 8 * (node & 3);
        unsigned s = 0;
#pragma unroll
        for (int k = 0; k < 16; ++k) {
            const int b = 16 * wv + k;  // slice
            s += (part[(size_t)(4 * b + q) * HWORDS_Q + lw] >> sh) & 255u;
        }
        cnt_p[wv][lane] = s;
    }

    __syncthreads();

    // ---- MFMA compute: m-tile = wv ----
    const int l15 = lane & 15;
    const int lhi = lane >> 4;  // 0..3

    // A frags: row = 16*wv + l15, k = ks*32 + lhi*8 + e
    const unsigned short* __restrict__ arow = &xs[(wv * 16 + l15) * XPAD + lhi * 8];
    const bf16x8 a0 = *reinterpret_cast<const bf16x8*>(arow + 0);
    const bf16x8 a1 = *reinterpret_cast<const bf16x8*>(arow + 32);

    // acc init = bias (depends only on output col) -> scale by count at store
    f32x4 acc[4];
#pragma unroll
    for (int nt = 0; nt < 4; ++nt) {
        const float b = bn[nt * 16 + l15];
        acc[nt] = f32x4{b, b, b, b};
    }

#pragma unroll
    for (int nt = 0; nt < 4; ++nt) {
        const unsigned short* __restrict__ brow =
            &wl[(nt * 16 + l15) * XPAD + lhi * 8];
        const bf16x8 b0 = *reinterpret_cast<const bf16x8*>(brow + 0);
        const bf16x8 b1 = *reinterpret_cast<const bf16x8*>(brow + 32);
        acc[nt] = __builtin_amdgcn_mfma_f32_16x16x32_bf16(a0, b0, acc[nt], 0, 0, 0);
        acc[nt] = __builtin_amdgcn_mfma_f32_16x16x32_bf16(a1, b1, acc[nt], 0, 0, 0);
    }

    // counts for this lane's 4 output rows: m = 16*wv + 4*lhi + r
    float cf[4];
#pragma unroll
    for (int r = 0; r < 4; ++r) {
        const int m = wv * 16 + lhi * 4 + r;
        cf[r] = (float)(cnt_p[0][m] + cnt_p[1][m] + cnt_p[2][m] + cnt_p[3][m]);
    }

    // store: D[m][n], m = 16*wv + 4*lhi + r, n = nt*16 + l15
#pragma unroll
    for (int nt = 0; nt < 4; ++nt) {
#pragma unroll
        for (int r = 0; r < 4; ++r) {
            const int node = base + wv * 16 + lhi * 4 + r;
            if (node < N_NODES)
                out[(size_t)node * D + nt * 16 + l15] = cf[r] * acc[nt][r];
        }
    }
}

extern "C" void kernel_launch(void* const* d_in, const int* in_sizes, int n_in,
                              void* d_out, int out_size, void* d_ws, size_t ws_size,
                              hipStream_t stream) {
    const float* nf   = (const float*)d_in[0];  // [100000, 64]
    const int*   eidx = (const int*)d_in[1];    // [2, 800000] int64 or int32
    const float* Wn   = (const float*)d_in[3];  // [64, 64]
    const float* bn   = (const float*)d_in[4];  // [64]
    float* out = (float*)d_out;                 // [100000, 64] f32

    unsigned* part = (unsigned*)d_ws;  // 256 x 25 KB = 6.42 MB slice-partials

    hist_kernel<<<HIST_BLOCKS, 1024, 0, stream>>>(eidx, part);

    proj_kernel<<<(N_NODES + 63) / 64, 256, 0, stream>>>(
        nf, Wn, bn, part, out);
}